// Round 5
// baseline (24008.461 us; speedup 1.0000x reference)
//
#include <hip/hip_runtime.h>
#include <hip/hip_bf16.h>
#include <math.h>

// Problem constants
#define B_  1024
#define T_  50
#define IN_ 784
#define N_  128
#define D_  40
#define H_  200
#define R_  4
#define C_  5
#define GAMMA_ 0.95f
#define G4H_ 800             // 4*H
#define PDIM_ 164            // R*(D+1)
#define RD_ 160              // R*D
#define OUTF_ 360            // H + R*D
#define MSZ_ 5120            // N*D
#define MST_ 41              // padded LDS stride for M rows (gcd(41,32)=1)
#define KP_ 800              // padded image K (25*32)
#define NBLK_ 1024           // persistent grid size

// recurrent GEMM hi/lo packing: K' = 36 k-blocks of 32 (12 hi + 12 hi + 12 lo on B)
#define AKB_ 24              // A k-blocks stored (hi 0..11, lo 12..23)
#define BKB_ 36
#define WXP_N 643072         // 25*800*32 + pad
#define W2P_N (BKB_ * G4H_ * 32)   // 921600
#define APK_N (AKB_ * B_ * 32)     // 786432

typedef __bf16 bf16x8 __attribute__((ext_vector_type(8)));
typedef __bf16 bf16x4 __attribute__((ext_vector_type(4)));
typedef float  fx4    __attribute__((ext_vector_type(4)));

__device__ __forceinline__ float sigmoidf_(float x) { return 1.f / (1.f + expf(-x)); }

__device__ __forceinline__ void load_lds16(const void* g, void* l) {
    __builtin_amdgcn_global_load_lds(
        (const __attribute__((address_space(1))) unsigned int*)g,
        (__attribute__((address_space(3))) unsigned int*)l, 16, 0, 0);
}

// ---------------------------------------------------------------------------
// Device-scope software grid barrier (sense-reversing via generation counter).
// Co-residency is guaranteed structurally: __launch_bounds__(256,4) caps
// VGPR at 128 -> exactly 4 blocks/CU capacity -> 1024 slots for 1024 blocks;
// no CU can take a 5th block, so the dispatcher fills all CUs evenly.
// ---------------------------------------------------------------------------
__device__ __forceinline__ void gbar(unsigned* cnt, unsigned* gen)
{
    __syncthreads();
    if (threadIdx.x == 0) {
        __threadfence();   // release: make this block's stores visible device-wide
        unsigned g = __atomic_load_n(gen, __ATOMIC_RELAXED);
        if (atomicAdd(cnt, 1u) == NBLK_ - 1u) {
            __atomic_store_n(cnt, 0u, __ATOMIC_RELAXED);
            __atomic_store_n(gen, g + 1u, __ATOMIC_RELEASE);
        } else {
            while (__atomic_load_n(gen, __ATOMIC_ACQUIRE) == g)
                __builtin_amdgcn_s_sleep(2);
        }
        __threadfence();   // acquire: invalidate stale L1/L2 before data reads
    }
    __syncthreads();
}

// ---------------------------------------------------------------------------
// One-time packing (see round-3 comments).
// ---------------------------------------------------------------------------
__global__ __launch_bounds__(256) void pack_kernel(
    const float* __restrict__ Wx, const float* __restrict__ Wh,
    __bf16* __restrict__ WxP, __bf16* __restrict__ W2P)
{
    int idx = blockIdx.x * 256 + threadIdx.x;
    if (idx < WXP_N) {
        int kb = idx / 25600, rem = idx - kb * 25600;
        int n = rem >> 5, q8 = rem & 31;
        int k = kb * 32 + q8;
        WxP[idx] = (k < IN_ && kb < 25) ? (__bf16)Wx[(size_t)k * G4H_ + n] : (__bf16)0.0f;
    }
    if (idx < W2P_N) {
        int kb = idx / (G4H_ * 32), rem = idx - kb * (G4H_ * 32);
        int n = rem >> 5, q8 = rem & 31;
        int kl = (kb < 12 ? kb : (kb < 24 ? kb - 12 : kb - 24)) * 32 + q8;
        __bf16 o = (__bf16)0.0f;
        if (kl < OUTF_) {
            float v = (kl < H_) ? Wh[(size_t)kl * G4H_ + n]
                                : Wx[(size_t)(789 + kl - H_) * G4H_ + n];
            __bf16 hi = (__bf16)v;
            o = (kb < 24) ? hi : (__bf16)(v - (float)hi);
        }
        W2P[idx] = o;
    }
}

// ---------------------------------------------------------------------------
// init state + barrier + loss accumulators
// ---------------------------------------------------------------------------
__global__ void init_kernel(float* Cst, float* Mg, float* wug, float* wrg,
                            __bf16* Apack, unsigned* bar, float* scal)
{
    size_t i = (size_t)blockIdx.x * blockDim.x + threadIdx.x;
    size_t stride = (size_t)gridDim.x * blockDim.x;
    for (size_t j = i; j < (size_t)B_ * MSZ_; j += stride) Mg[j] = 1e-6f;
    for (size_t j = i; j < (size_t)B_ * H_; j += stride) Cst[j] = 0.f;
    for (size_t j = i; j < (size_t)B_ * N_; j += stride) wug[j] = ((j & (N_ - 1)) == 0) ? 1.f : 0.f;
    for (size_t j = i; j < (size_t)B_ * R_ * N_; j += stride) wrg[j] = ((j & (N_ - 1)) == 0) ? 1.f : 0.f;
    for (size_t j = i; j < (size_t)APK_N; j += stride) {
        int kb = (int)(j >> 15);
        int q8 = (int)(j & 31);
        int kl = (kb % 12) * 32 + q8;
        float v = (kl >= H_ && kl < OUTF_) ? 1e-6f : 0.f;
        __bf16 hi = (__bf16)v;
        Apack[j] = (kb < 12) ? hi : (__bf16)(v - (float)hi);
    }
    if (i < 2) { scal[i] = 0.f; bar[i] = 0u; }
}

// ---------------------------------------------------------------------------
// Convert ALL images to bf16, rows m = t*B + b, K padded to 800.
// ---------------------------------------------------------------------------
__global__ __launch_bounds__(256) void img_convert(
    const float* __restrict__ images, __bf16* __restrict__ img)
{
    long long gi = (long long)blockIdx.x * 256 + threadIdx.x;
    if (gi * 4 >= (long long)T_ * B_ * KP_) return;
    long long m = (gi * 4) / KP_;
    int k = (int)((gi * 4) - m * KP_);
    int t = (int)(m >> 10), b = (int)(m & (B_ - 1));
    bf16x4 o;
    if (k < IN_) {
        const float4 v = *(const float4*)&images[((size_t)b * T_ + t) * IN_ + k];
        o[0] = (__bf16)v.x; o[1] = (__bf16)v.y; o[2] = (__bf16)v.z; o[3] = (__bf16)v.w;
    } else {
        o[0] = o[1] = o[2] = o[3] = (__bf16)0.0f;
    }
    *(bf16x4*)&img[(size_t)m * KP_ + k] = o;
}

// ---------------------------------------------------------------------------
// Gx[t][b][col] = img_row @ WxBf + b_lstm[col] + Wx[784+prev_label][col]
// ---------------------------------------------------------------------------
__global__ __launch_bounds__(256) void gx_mfma(
    const __bf16* __restrict__ img, const __bf16* __restrict__ WxP,
    const int* __restrict__ labels, const float* __restrict__ Wx,
    const float* __restrict__ b_lstm, float* __restrict__ Gx)
{
    __shared__ __bf16 A_lds[4096];
    __shared__ __bf16 B_lds[2048];

    const int tid  = threadIdx.x;
    const int lane = tid & 63, w = tid >> 6;
    const int quad = lane >> 4, ln = lane & 15;
    const int swzl = (ln & 3) ^ ((ln >> 2) & 3);
    const int row0 = blockIdx.x * 128;
    const int n0   = blockIdx.y * 64;
    const int mw   = (w >> 1) * 64;
    const int nw   = (w & 1) * 32;

    fx4 acc[4][2];
    #pragma unroll
    for (int i = 0; i < 4; i++)
        #pragma unroll
        for (int j = 0; j < 2; j++) acc[i][j] = (fx4)0.0f;

    for (int kb = 0; kb < 25; kb++) {
        #pragma unroll
        for (int p = 0; p < 2; p++) {
            int cc = p * 256 + tid;
            int m = cc >> 2, c = cc & 3;
            int q = c ^ ((m & 3) ^ ((m >> 2) & 3));
            load_lds16(img + (size_t)(row0 + m) * KP_ + kb * 32 + q * 8,
                       &A_lds[(size_t)(p * 256 + w * 64) * 8]);
        }
        {
            int n = tid >> 2, c = tid & 3;
            int q = c ^ ((n & 3) ^ ((n >> 2) & 3));
            load_lds16(WxP + ((size_t)kb * G4H_ + n0 + n) * 32 + q * 8,
                       &B_lds[(size_t)(w * 64) * 8]);
        }
        __syncthreads();

        bf16x8 a[4], bb[2];
        #pragma unroll
        for (int mi = 0; mi < 4; mi++)
            a[mi] = *(const bf16x8*)&A_lds[((mw + mi * 16 + ln) * 4 + (quad ^ swzl)) * 8];
        #pragma unroll
        for (int ni = 0; ni < 2; ni++)
            bb[ni] = *(const bf16x8*)&B_lds[((nw + ni * 16 + ln) * 4 + (quad ^ swzl)) * 8];
        #pragma unroll
        for (int mi = 0; mi < 4; mi++)
            #pragma unroll
            for (int ni = 0; ni < 2; ni++)
                acc[mi][ni] = __builtin_amdgcn_mfma_f32_16x16x32_bf16(a[mi], bb[ni], acc[mi][ni], 0, 0, 0);
        __syncthreads();
    }

    #pragma unroll
    for (int mi = 0; mi < 4; mi++) {
        #pragma unroll
        for (int rr = 0; rr < 4; rr++) {
            int row = row0 + mw + mi * 16 + quad * 4 + rr;
            int t = row >> 10, b = row & (B_ - 1);
            int lbl = (t > 0) ? labels[b * T_ + t - 1] : -1;
            #pragma unroll
            for (int ni = 0; ni < 2; ni++) {
                int col = n0 + nw + ni * 16 + ln;
                if (col < G4H_) {
                    float add = b_lstm[col];
                    if (lbl >= 0) add += Wx[(size_t)(IN_ + lbl) * G4H_ + col];
                    Gx[(size_t)row * G4H_ + col] = acc[mi][ni][rr] + add;
                }
            }
        }
    }
}

// ---------------------------------------------------------------------------
// Phase-B shared-memory layout
// ---------------------------------------------------------------------------
struct StepShared {
    float M[N_ * MST_];
    float h[H_];
    float k[RD_];
    float sig[R_];
    float wu[N_];
    int   lu[R_];
    float wrn[R_ * N_];
    float ww[R_ * N_];
    float rn[RD_];
    float red[160];
};

// ---------------------------------------------------------------------------
// Phase A: one 64x32 tile of gates = Gx_t + Apack@W2P (hi/lo bf16 MFMA)
// ---------------------------------------------------------------------------
__device__ __forceinline__ void rec_gemm_tile(
    int tile, const __bf16* __restrict__ Apack, const __bf16* __restrict__ W2P,
    const float* __restrict__ Gxt, float* __restrict__ gates,
    __bf16* A_lds, __bf16* B_lds)
{
    const int tid  = threadIdx.x;
    const int lane = tid & 63, w = tid >> 6;
    const int quad = lane >> 4, ln = lane & 15;
    const int swzl = (ln & 3) ^ ((ln >> 2) & 3);
    const int row0 = (tile & 15) * 64;
    const int col0 = (tile >> 4) * 32;
    const int mw   = (w >> 1) * 32;
    const int nw   = (w & 1) * 16;

    fx4 acc[2];
    acc[0] = (fx4)0.0f; acc[1] = (fx4)0.0f;

    for (int it = 0; it < 18; it++) {
        #pragma unroll
        for (int p = 0; p < 2; p++) {
            int cc = p * 256 + tid;
            int kbl = cc >> 8, row = (cc >> 2) & 63, c = cc & 3;
            int q = c ^ ((row & 3) ^ ((row >> 2) & 3));
            int kbg = it * 2 + kbl;
            int kba = (kbg < AKB_) ? kbg : kbg - AKB_;
            load_lds16(Apack + ((size_t)kba * B_ + row0 + row) * 32 + q * 8,
                       &A_lds[(size_t)(p * 256 + w * 64) * 8]);
        }
        {
            int kbl = tid >> 7, n = (tid >> 2) & 31, c = tid & 3;
            int q = c ^ ((n & 3) ^ ((n >> 2) & 3));
            int kbg = it * 2 + kbl;
            load_lds16(W2P + ((size_t)kbg * G4H_ + col0 + n) * 32 + q * 8,
                       &B_lds[(size_t)(w * 64) * 8]);
        }
        __syncthreads();

        #pragma unroll
        for (int s = 0; s < 2; s++) {
            bf16x8 a0 = *(const bf16x8*)&A_lds[((s * 64 + mw + ln) * 4 + (quad ^ swzl)) * 8];
            bf16x8 a1 = *(const bf16x8*)&A_lds[((s * 64 + mw + 16 + ln) * 4 + (quad ^ swzl)) * 8];
            bf16x8 b0 = *(const bf16x8*)&B_lds[((s * 32 + nw + ln) * 4 + (quad ^ swzl)) * 8];
            acc[0] = __builtin_amdgcn_mfma_f32_16x16x32_bf16(a0, b0, acc[0], 0, 0, 0);
            acc[1] = __builtin_amdgcn_mfma_f32_16x16x32_bf16(a1, b0, acc[1], 0, 0, 0);
        }
        __syncthreads();
    }

    #pragma unroll
    for (int mi = 0; mi < 2; mi++) {
        #pragma unroll
        for (int rr = 0; rr < 4; rr++) {
            int row = row0 + mw + mi * 16 + quad * 4 + rr;
            int col = col0 + nw + ln;
            gates[(size_t)row * G4H_ + col] = acc[mi][rr] + Gxt[(size_t)row * G4H_ + col];
        }
    }
}

// ---------------------------------------------------------------------------
// Phase B: LSTM + LRUA step for sequence b (identical numerics to round 3).
// ---------------------------------------------------------------------------
__device__ __forceinline__ void lrua_step(
    int b, int t, const float* __restrict__ gates, __bf16* __restrict__ Apack,
    float* __restrict__ Cst, float* __restrict__ Mg,
    float* __restrict__ wug, float* __restrict__ wrg,
    const float* __restrict__ Wp, const float* __restrict__ bp,
    const float* __restrict__ Wc, const float* __restrict__ bc,
    float* __restrict__ out, StepShared& ss)
{
    const int tid = threadIdx.x;
    const int lane = tid & 63, w = tid >> 6;

    // P1: LSTM + state loads
    if (tid < H_) {
        const float gi = gates[(size_t)b * G4H_ + tid];
        const float gf = gates[(size_t)b * G4H_ + H_ + tid];
        const float gg = gates[(size_t)b * G4H_ + 2 * H_ + tid];
        const float go = gates[(size_t)b * G4H_ + 3 * H_ + tid];
        const float c_old = Cst[b * H_ + tid];
        const float cn = sigmoidf_(gf) * c_old + sigmoidf_(gi) * tanhf(gg);
        const float hn = sigmoidf_(go) * tanhf(cn);
        Cst[b * H_ + tid] = cn;
        ss.h[tid] = hn;
        __bf16 hi = (__bf16)hn;
        __bf16 lo = (__bf16)(hn - (float)hi);
        const int kb = tid >> 5, q8 = tid & 31;
        Apack[((size_t)kb * B_ + b) * 32 + q8] = hi;
        Apack[((size_t)(kb + 12) * B_ + b) * 32 + q8] = lo;
    }
    if (tid < N_) ss.wu[tid] = wug[b * N_ + tid];
    {
        const float4* Msrc = (const float4*)(Mg + (size_t)b * MSZ_);
        #pragma unroll
        for (int p = 0; p < 5; p++) {
            int li4 = p * 256 + tid;
            int n = li4 / 10, d0 = (li4 - n * 10) * 4;
            float4 v = Msrc[li4];
            float* dst = &ss.M[n * MST_ + d0];
            dst[0] = v.x; dst[1] = v.y; dst[2] = v.z; dst[3] = v.w;
        }
    }
    __syncthreads();

    // P2: Wp projection (tid<164) || top-4 least-used (wave 3)
    if (tid < PDIM_) {
        float acc = bp[tid];
        #pragma unroll 4
        for (int k2 = 0; k2 < H_; k2++) acc += ss.h[k2] * Wp[k2 * PDIM_ + tid];
        int r = tid / (D_ + 1), d = tid - r * (D_ + 1);
        if (d < D_) ss.k[r * D_ + d] = tanhf(acc);
        else        ss.sig[r] = sigmoidf_(acc);
    }
    if (w == 3) {
        float v0 = ss.wu[lane], v1 = ss.wu[lane + 64];
        #pragma unroll
        for (int r4 = 0; r4 < R_; r4++) {
            float v; int idx;
            if (v1 < v0) { v = v1; idx = lane + 64; } else { v = v0; idx = lane; }
            #pragma unroll
            for (int off = 32; off > 0; off >>= 1) {
                float ov = __shfl_down(v, off);
                int   oi = __shfl_down(idx, off);
                if (ov < v || (ov == v && oi < idx)) { v = ov; idx = oi; }
            }
            int bi = __shfl(idx, 0);
            if (lane == 0) ss.lu[r4] = bi;
            if (lane == bi) v0 = 3.0e38f;
            if (lane + 64 == bi) v1 = 3.0e38f;
        }
    }
    __syncthreads();

    // P3: row-normalized cosine scores
    #pragma unroll
    for (int p = 0; p < 2; p++) {
        int li = p * 256 + tid;
        int r = li >> 7, n = li & (N_ - 1);
        float dot = 0.f, nrm = 0.f;
        #pragma unroll
        for (int d = 0; d < D_; d++) {
            float mv = ss.M[n * MST_ + d];
            dot += ss.k[r * D_ + d] * mv;
            nrm += mv * mv;
        }
        ss.wrn[li] = dot / (sqrtf(nrm) + 1e-8f);
    }
    __syncthreads();

    // P4: per-head (wave r): kinv, softmax, write weights, store wrg
    {
        const int r = w;
        float kv = (lane < D_) ? ss.k[r * D_ + lane] * ss.k[r * D_ + lane] : 0.f;
        #pragma unroll
        for (int off = 32; off > 0; off >>= 1) kv += __shfl_xor(kv, off);
        const float kinv = 1.f / (sqrtf(kv) + 1e-8f);

        const int n0i = lane, n1i = lane + 64;
        float s0 = ss.wrn[r * N_ + n0i] * kinv;
        float s1 = ss.wrn[r * N_ + n1i] * kinv;
        const float sg = ss.sig[r];
        float wlu0 = (n0i == ss.lu[0] || n0i == ss.lu[1] || n0i == ss.lu[2] || n0i == ss.lu[3]) ? 1.f : 0.f;
        float wlu1 = (n1i == ss.lu[0] || n1i == ss.lu[1] || n1i == ss.lu[2] || n1i == ss.lu[3]) ? 1.f : 0.f;
        ss.ww[r * N_ + n0i] = sg * wrg[(size_t)b * (R_ * N_) + r * N_ + n0i] + (1.f - sg) * wlu0;
        ss.ww[r * N_ + n1i] = sg * wrg[(size_t)b * (R_ * N_) + r * N_ + n1i] + (1.f - sg) * wlu1;
        float mx = fmaxf(s0, s1);
        #pragma unroll
        for (int off = 32; off > 0; off >>= 1) mx = fmaxf(mx, __shfl_xor(mx, off));
        float e0 = expf(s0 - mx), e1 = expf(s1 - mx);
        float sm = e0 + e1;
        #pragma unroll
        for (int off = 32; off > 0; off >>= 1) sm += __shfl_xor(sm, off);
        const float inv = 1.f / sm;
        e0 *= inv; e1 *= inv;
        ss.wrn[r * N_ + n0i] = e0;
        ss.wrn[r * N_ + n1i] = e1;
        wrg[(size_t)b * (R_ * N_) + r * N_ + n0i] = e0;
        wrg[(size_t)b * (R_ * N_) + r * N_ + n1i] = e1;
    }
    __syncthreads();

    // P5: usage update + memory erase/write (float4 writeback)
    if (tid < N_) {
        float acc = GAMMA_ * ss.wu[tid];
        #pragma unroll
        for (int r = 0; r < R_; r++) acc += ss.wrn[r * N_ + tid] + ss.ww[r * N_ + tid];
        wug[b * N_ + tid] = acc;
    }
    {
        const int lu4 = ss.lu[3];
        float4* Mdst = (float4*)(Mg + (size_t)b * MSZ_);
        #pragma unroll
        for (int p = 0; p < 5; p++) {
            int li4 = p * 256 + tid;
            int n = li4 / 10, d0 = (li4 - n * 10) * 4;
            const float w0 = ss.ww[n], w1 = ss.ww[N_ + n];
            const float w2 = ss.ww[2 * N_ + n], w3 = ss.ww[3 * N_ + n];
            float4 vout;
            float* vp = &vout.x;
            #pragma unroll
            for (int j = 0; j < 4; j++) {
                int d = d0 + j;
                float mv = (n == lu4) ? 0.f : ss.M[n * MST_ + d];
                mv += w0 * ss.k[d] + w1 * ss.k[D_ + d]
                    + w2 * ss.k[2 * D_ + d] + w3 * ss.k[3 * D_ + d];
                ss.M[n * MST_ + d] = mv;
                vp[j] = mv;
            }
            Mdst[li4] = vout;
        }
    }
    __syncthreads();

    // P6: read vectors from updated memory; write r to Apack (hi/lo)
    if (tid < RD_) {
        int r = tid / D_, d = tid - r * D_;
        float acc = 0.f;
        for (int n = 0; n < N_; n++) acc += ss.wrn[r * N_ + n] * ss.M[n * MST_ + d];
        ss.rn[tid] = acc;
        __bf16 hi = (__bf16)acc;
        __bf16 lo = (__bf16)(acc - (float)hi);
        const int kp = H_ + tid;
        const int kb = kp >> 5, q8 = kp & 31;
        Apack[((size_t)kb * B_ + b) * 32 + q8] = hi;
        Apack[((size_t)(kb + 12) * B_ + b) * 32 + q8] = lo;
    }
    __syncthreads();

    // P7: logits partials (5 cols x 32 segments)
    if (tid < 160) {
        int c = tid >> 5, seg = tid & 31;
        float acc = 0.f;
        for (int j = seg; j < OUTF_; j += 32) {
            float v = (j < H_) ? ss.h[j] : ss.rn[j - H_];
            acc += v * Wc[j * C_ + c];
        }
        ss.red[tid] = acc;
    }
    __syncthreads();

    // P8: finish logits, softmax, write probs
    if (w == 0) {
        float lg = 0.f;
        if (lane < C_) {
            lg = bc[lane];
            #pragma unroll
            for (int s = 0; s < 32; s++) lg += ss.red[lane * 32 + s];
        }
        float l0 = __shfl(lg, 0), l1 = __shfl(lg, 1), l2 = __shfl(lg, 2);
        float l3 = __shfl(lg, 3), l4 = __shfl(lg, 4);
        if (lane == 0) {
            float mx = fmaxf(fmaxf(fmaxf(l0, l1), fmaxf(l2, l3)), l4);
            float e0 = expf(l0 - mx), e1 = expf(l1 - mx), e2 = expf(l2 - mx);
            float e3 = expf(l3 - mx), e4 = expf(l4 - mx);
            float inv = 1.f / (e0 + e1 + e2 + e3 + e4);
            float* o = out + ((size_t)b * T_ + t) * C_;
            o[0] = e0 * inv; o[1] = e1 * inv; o[2] = e2 * inv; o[3] = e3 * inv; o[4] = e4 * inv;
        }
    }
    __syncthreads();
}

// ---------------------------------------------------------------------------
// Persistent kernel: full 50-step recurrence in ONE normal launch.
// 1024 blocks x 256 threads, 4 blocks/CU (forced by launch bounds).
// ---------------------------------------------------------------------------
__global__ __launch_bounds__(256, 4) void persist_kernel(
    __bf16* __restrict__ Apack, const __bf16* __restrict__ W2P,
    const float* __restrict__ Gx, float* __restrict__ gates,
    float* __restrict__ Cst, float* __restrict__ Mg,
    float* __restrict__ wug, float* __restrict__ wrg,
    const float* __restrict__ Wp, const float* __restrict__ bp,
    const float* __restrict__ Wc, const float* __restrict__ bc,
    float* __restrict__ out, unsigned* __restrict__ bar)
{
    __shared__ union {
        struct { __bf16 A[4096]; __bf16 Bl[2048]; } g;   // phase A: 12 KB
        StepShared s;                                     // phase B: ~27.7 KB
    } sh;

    const int blk = blockIdx.x;

    for (int t = 0; t < T_; t++) {
        if (blk < 400)
            rec_gemm_tile(blk, Apack, W2P, Gx + (size_t)t * B_ * G4H_, gates,
                          sh.g.A, sh.g.Bl);
        gbar(&bar[0], &bar[1]);
        lrua_step(blk, t, gates, Apack, Cst, Mg, wug, wrg, Wp, bp, Wc, bc, out, sh.s);
        gbar(&bar[0], &bar[1]);
    }
}

// ---------------------------------------------------------------------------
// loss = mean(logsumexp(probs) - probs[tgt]); acc = mean(argmax==tgt)
// ---------------------------------------------------------------------------
__global__ __launch_bounds__(256) void loss_kernel(
    const float* __restrict__ out, const int* __restrict__ labels, float* __restrict__ la)
{
    int row = blockIdx.x * 256 + threadIdx.x;
    float li = 0.f, ai = 0.f;
    if (row < B_ * T_) {
        float p[C_];
        #pragma unroll
        for (int c = 0; c < C_; c++) p[c] = out[(size_t)row * C_ + c];
        int tgt = labels[row];
        float mx = p[0];
        #pragma unroll
        for (int c = 1; c < C_; c++) mx = fmaxf(mx, p[c]);
        float sm = 0.f;
        #pragma unroll
        for (int c = 0; c < C_; c++) sm += expf(p[c] - mx);
        li = (mx + logf(sm) - p[tgt]) * (1.f / (B_ * T_));
        int pred = 0; float bv = p[0];
        #pragma unroll
        for (int c = 1; c < C_; c++) if (p[c] > bv) { bv = p[c]; pred = c; }
        ai = (pred == tgt) ? (1.f / (B_ * T_)) : 0.f;
    }
    for (int off = 32; off > 0; off >>= 1) {
        li += __shfl_down(li, off);
        ai += __shfl_down(ai, off);
    }
    if ((threadIdx.x & 63) == 0) {
        atomicAdd(&la[0], li);
        atomicAdd(&la[1], ai);
    }
}

extern "C" void kernel_launch(void* const* d_in, const int* in_sizes, int n_in,
                              void* d_out, int out_size, void* d_ws, size_t ws_size,
                              hipStream_t stream)
{
    const float* images = (const float*)d_in[0];
    const int*   labels = (const int*)d_in[1];
    const float* Wx     = (const float*)d_in[2];
    const float* Wh     = (const float*)d_in[3];
    const float* b_lstm = (const float*)d_in[4];
    const float* Wp     = (const float*)d_in[5];
    const float* bp     = (const float*)d_in[6];
    const float* Wc     = (const float*)d_in[7];
    const float* bc     = (const float*)d_in[8];
    float* out = (float*)d_out;

    float* ws = (float*)d_ws;
    float* gates = ws;                             // 1024*800
    float* Cst   = gates + (size_t)B_ * G4H_;      // 1024*200
    float* Mg    = Cst   + (size_t)B_ * H_;        // 1024*5120
    float* wug   = Mg    + (size_t)B_ * MSZ_;      // 1024*128
    float* wrg   = wug   + (size_t)B_ * N_;        // 1024*512
    float* Gx    = wrg   + (size_t)B_ * R_ * N_;   // 50*1024*800 f32
    __bf16* imgb = (__bf16*)(Gx + (size_t)T_ * B_ * G4H_);   // 50*1024*800 bf16
    __bf16* WxP  = imgb + (size_t)T_ * B_ * KP_;
    __bf16* W2P  = WxP  + (size_t)WXP_N;
    __bf16* Apack = W2P + (size_t)W2P_N;
    unsigned* bar = (unsigned*)(Apack + (size_t)APK_N + 64);

    pack_kernel<<<(W2P_N + 255) / 256, 256, 0, stream>>>(Wx, Wh, WxP, W2P);
    init_kernel<<<1024, 256, 0, stream>>>(Cst, Mg, wug, wrg, Apack, bar,
                                          out + (size_t)B_ * T_ * C_);

    img_convert<<<(int)(((long long)T_ * B_ * KP_ / 4 + 255) / 256), 256, 0, stream>>>(images, imgb);
    gx_mfma<<<dim3(T_ * B_ / 128, 13), 256, 0, stream>>>(imgb, WxP, labels, Wx, b_lstm, Gx);

    persist_kernel<<<NBLK_, 256, 0, stream>>>(
        Apack, W2P, Gx, gates, Cst, Mg, wug, wrg, Wp, bp, Wc, bc, out, bar);

    loss_kernel<<<(B_ * T_) / 256, 256, 0, stream>>>(out, labels, out + (size_t)B_ * T_ * C_);
}